// Round 1
// baseline (239.607 us; speedup 1.0000x reference)
//
#include <hip/hip_runtime.h>
#include <stdint.h>

#define BATCH 16
#define NPIX 200704   // 448*448
#define HB 64
#define EPS 1e-6f

// ---------------- zero scratch (fine histograms) ----------------
__global__ void zero_u128(uint4* __restrict__ p, int n) {
  int i = blockIdx.x * blockDim.x + threadIdx.x;
  int stride = gridDim.x * blockDim.x;
  uint4 z = make_uint4(0u, 0u, 0u, 0u);
  for (; i < n; i += stride) p[i] = z;
}

// ---------------- constant kernel table K[j][g] = k(c_j - b_g) ----------------
__global__ void build_ktable(float* __restrict__ kt, int W) {
  int idx = blockIdx.x * 256 + threadIdx.x;
  if (idx >= W * HB) return;
  int j = idx >> 6, g = idx & 63;
  float c = ((float)j + 0.5f) / (float)W;
  float bb = (float)g / 63.0f;
  float d = (c - bb) * 50.0f;           // 1/sigma = 50
  kt[idx] = 1.0f / (1.0f + d * d);
}

// ---------------- stage A: chroma computation + fine binning ----------------
__global__ __launch_bounds__(256) void bin_pixels(const float* __restrict__ x,
                                                  unsigned int* __restrict__ Hh,
                                                  int W) {
  int gid = blockIdx.x * 256 + threadIdx.x;          // covers BATCH*NPIX/4 exactly
  int b = gid / (NPIX / 4);
  int q = gid - b * (NPIX / 4);
  const float4* R  = (const float4*)(x + (size_t)b * 3 * NPIX);
  const float4* G  = R + (NPIX / 4);
  const float4* Bl = G + (NPIX / 4);
  float4 rv = R[q], gv = G[q], bv = Bl[q];
  unsigned int* Hb = Hh + (size_t)b * W * W;
  float fW = (float)W;
  float rr[4] = {rv.x, rv.y, rv.z, rv.w};
  float gg[4] = {gv.x, gv.y, gv.z, gv.w};
  float bb[4] = {bv.x, bv.y, bv.z, bv.w};
#pragma unroll
  for (int t = 0; t < 4; t++) {
    float r  = fminf(fmaxf(rr[t], 0.0f), 1.0f);
    float g  = fminf(fmaxf(gg[t], 0.0f), 1.0f);
    float bl = fminf(fmaxf(bb[t], 0.0f), 1.0f);
    float s = r + g + bl + EPS;
    float inv = 1.0f / s;
    int i = (int)(r * inv * fW);
    int j = (int)(g * inv * fW);
    i = min(i, W - 1);
    j = min(j, W - 1);
    atomicAdd(&Hb[(size_t)i * W + j], 1u);
  }
}

// ---------------- stage B: M[b][q][i][g] = sum_{j in q-slice} H[i][j] * K[j][g] ----------------
__global__ __launch_bounds__(256) void stageB(const unsigned int* __restrict__ Hh,
                                              const float* __restrict__ kt,
                                              float* __restrict__ M, int W, int Q) {
  int ntile = W >> 6;
  int bid = blockIdx.x;
  int q = bid % Q;
  int itile = (bid / Q) % ntile;
  int b = bid / (Q * ntile);
  __shared__ float sH[64][65];   // +1 pad: conflict-free row reads
  __shared__ float sK[64][64];   // read as float4, 16 distinct addrs/wave
  int tid = threadIdx.x;
  int gq4 = (tid & 15) * 4;
  int iq4 = (tid >> 4) * 4;
  float acc[4][4];
#pragma unroll
  for (int a = 0; a < 4; a++)
#pragma unroll
    for (int c = 0; c < 4; c++) acc[a][c] = 0.0f;

  int jspan = W / Q;            // 128
  int jbase = q * jspan;
  int nchunk = jspan >> 6;      // 2
  const unsigned int* Hbase = Hh + ((size_t)b * W + (size_t)itile * 64) * W;

  for (int ch = 0; ch < nchunk; ch++) {
    int j0 = jbase + ch * 64;
#pragma unroll
    for (int rep = 0; rep < 16; rep++) {
      int idx = rep * 256 + tid;
      int ii = idx >> 6, jj = idx & 63;
      sH[ii][jj] = (float)Hbase[(size_t)ii * W + (j0 + jj)];
      sK[ii][jj] = kt[(size_t)(j0 + ii) * HB + jj];
    }
    __syncthreads();
#pragma unroll 8
    for (int jp = 0; jp < 64; jp++) {
      float4 kv = *(const float4*)&sK[jp][gq4];
      float h[4];
#pragma unroll
      for (int di = 0; di < 4; di++) h[di] = sH[iq4 + di][jp];
      float kk[4] = {kv.x, kv.y, kv.z, kv.w};
#pragma unroll
      for (int di = 0; di < 4; di++)
#pragma unroll
        for (int dg = 0; dg < 4; dg++)
          acc[di][dg] = fmaf(h[di], kk[dg], acc[di][dg]);
    }
    __syncthreads();
  }

  float* Mb = M + (((size_t)b * Q + q) * W + (size_t)itile * 64) * HB;
#pragma unroll
  for (int di = 0; di < 4; di++) {
    float4 v = make_float4(acc[di][0], acc[di][1], acc[di][2], acc[di][3]);
    *(float4*)&Mb[(size_t)(iq4 + di) * HB + gq4] = v;
  }
}

// ---------------- stage C: partial hist P[b][chunk][r][g] = sum_{i in chunk} K[i][r] * Msum[i][g] ----------------
__global__ __launch_bounds__(1024) void stageC(const float* __restrict__ M,
                                               const float* __restrict__ kt,
                                               float* __restrict__ P, int W, int Q) {
  int ntile = W >> 6;
  int b = blockIdx.x / ntile;
  int cti = blockIdx.x % ntile;
  int i0 = cti * 64;
  __shared__ float sM[64][64];
  __shared__ float sK[64][65];
  int tid = threadIdx.x;
  int r = tid >> 4;
  int g4 = (tid & 15) * 4;
#pragma unroll
  for (int rep = 0; rep < 4; rep++) {
    int idx = rep * 1024 + tid;
    int ii = idx >> 6, cc = idx & 63;
    float v = 0.0f;
    for (int q = 0; q < Q; q++)
      v += M[(((size_t)b * Q + q) * W + (i0 + ii)) * HB + cc];
    sM[ii][cc] = v;
    sK[ii][cc] = kt[(size_t)(i0 + ii) * HB + cc];
  }
  __syncthreads();
  float a0 = 0, a1 = 0, a2 = 0, a3 = 0;
#pragma unroll 8
  for (int ip = 0; ip < 64; ip++) {
    float kv = sK[ip][r];
    float4 m = *(const float4*)&sM[ip][g4];
    a0 = fmaf(kv, m.x, a0);
    a1 = fmaf(kv, m.y, a1);
    a2 = fmaf(kv, m.z, a2);
    a3 = fmaf(kv, m.w, a3);
  }
  float* Pb = P + ((size_t)b * ntile + cti) * 4096;
  *(float4*)&Pb[(size_t)r * 64 + g4] = make_float4(a0, a1, a2, a3);
}

// ---------------- stage D: fixed-order reduce over chunks + normalize ----------------
__global__ __launch_bounds__(256) void stageD(const float* __restrict__ P,
                                              float* __restrict__ out, int W) {
  int ntile = W >> 6;
  int b = blockIdx.x;
  int tid = threadIdx.x;
  const float* Pb = P + (size_t)b * ntile * 4096;
  float un[16];
  float psum = 0.0f;
#pragma unroll
  for (int t = 0; t < 16; t++) {
    int rg = t * 256 + tid;
    float s = 0.0f;
    for (int c = 0; c < ntile; c++) s += Pb[(size_t)c * 4096 + rg];
    un[t] = s;
    psum += s;
  }
  __shared__ float red[256];
  red[tid] = psum;
  __syncthreads();
  for (int s = 128; s > 0; s >>= 1) {
    if (tid < s) red[tid] += red[tid + s];
    __syncthreads();
  }
  float inv = 1.0f / (red[0] + EPS);
#pragma unroll
  for (int t = 0; t < 16; t++) {
    out[(size_t)b * 4096 + t * 256 + tid] = un[t] * inv;
  }
}

extern "C" void kernel_launch(void* const* d_in, const int* in_sizes, int n_in,
                              void* d_out, int out_size, void* d_ws, size_t ws_size,
                              hipStream_t stream) {
  const float* x = (const float*)d_in[0];
  float* out = (float*)d_out;

  // choose fine-grid size W by available workspace (512 preferred)
  int W = 512;
  for (;;) {
    int Qtry = W >> 7;
    size_t need = (size_t)W * HB * 4                    // K table
                + (size_t)BATCH * W * W * 4             // H counts
                + (size_t)BATCH * Qtry * W * HB * 4     // M partials
                + (size_t)BATCH * (W >> 6) * 4096 * 4;  // P partial hists
    if (need <= ws_size || W == 128) break;
    W >>= 1;
  }
  int Q = W >> 7;        // j-slices in stage B (parallelism)
  int ntile = W >> 6;

  char* p = (char*)d_ws;
  float* kt = (float*)p;          p += (size_t)W * HB * 4;
  unsigned int* Hh = (unsigned int*)p; p += (size_t)BATCH * W * W * 4;
  float* M = (float*)p;           p += (size_t)BATCH * Q * W * HB * 4;
  float* P = (float*)p;

  int hquads = BATCH * W * W / 4;
  zero_u128<<<1024, 256, 0, stream>>>((uint4*)Hh, hquads);
  build_ktable<<<(W * HB + 255) / 256, 256, 0, stream>>>(kt, W);
  bin_pixels<<<BATCH * (NPIX / 4) / 256, 256, 0, stream>>>(x, Hh, W);
  stageB<<<BATCH * ntile * Q, 256, 0, stream>>>(Hh, kt, M, W, Q);
  stageC<<<BATCH * ntile, 1024, 0, stream>>>(M, kt, P, W, Q);
  stageD<<<BATCH, 256, 0, stream>>>(P, out, W);
}

// Round 2
// 112.216 us; speedup vs baseline: 2.1352x; 2.1352x over previous
//
#include <hip/hip_runtime.h>
#include <stdint.h>

#define BATCH 16
#define NPIX 200704   // 448*448
#define HB 64
#define EPS 1e-6f
#define WINWORDS 16384   // 64 KB LDS window (uint)

// ---------------- constant kernel table K[j][g] = k(c_j - b_g) ----------------
__global__ void build_ktable(float* __restrict__ kt, int W) {
  int idx = blockIdx.x * 256 + threadIdx.x;
  if (idx >= W * HB) return;
  int j = idx >> 6, g = idx & 63;
  float c = ((float)j + 0.5f) / (float)W;
  float bb = (float)g / 63.0f;
  float d = (c - bb) * 50.0f;           // 1/sigma = 50
  kt[idx] = 1.0f / (1.0f + d * d);
}

// ---------------- pass 1: chroma -> fine-grid id per pixel ----------------
__global__ __launch_bounds__(256) void make_ids(const float* __restrict__ x,
                                                unsigned int* __restrict__ ids,
                                                int W) {
  int gid = blockIdx.x * 256 + threadIdx.x;          // covers BATCH*NPIX/4 exactly
  int b = gid / (NPIX / 4);
  int q = gid - b * (NPIX / 4);
  const float4* R  = (const float4*)(x + (size_t)b * 3 * NPIX);
  const float4* G  = R + (NPIX / 4);
  const float4* Bl = G + (NPIX / 4);
  float4 rv = R[q], gv = G[q], bv = Bl[q];
  float fW = (float)W;
  float rr[4] = {rv.x, rv.y, rv.z, rv.w};
  float gg[4] = {gv.x, gv.y, gv.z, gv.w};
  float bb[4] = {bv.x, bv.y, bv.z, bv.w};
  unsigned int o[4];
#pragma unroll
  for (int t = 0; t < 4; t++) {
    float r  = fminf(fmaxf(rr[t], 0.0f), 1.0f);
    float g  = fminf(fmaxf(gg[t], 0.0f), 1.0f);
    float bl = fminf(fmaxf(bb[t], 0.0f), 1.0f);
    float inv = 1.0f / (r + g + bl + EPS);
    int i = min((int)(r * inv * fW), W - 1);
    int j = min((int)(g * inv * fW), W - 1);
    o[t] = (unsigned int)(i * W + j);
  }
  ((uint4*)(ids + (size_t)b * NPIX))[q] = make_uint4(o[0], o[1], o[2], o[3]);
}

// ---------------- pass 2: per-(batch,window) LDS histogram, exclusive flush ----------------
__global__ __launch_bounds__(1024) void hist_window(const unsigned int* __restrict__ ids,
                                                    unsigned int* __restrict__ Hh,
                                                    int nwin) {
  __shared__ unsigned int sh[WINWORDS];
  int b = blockIdx.x / nwin;
  unsigned int w = (unsigned int)(blockIdx.x % nwin);
  int tid = threadIdx.x;
  for (int t = tid; t < WINWORDS; t += 1024) sh[t] = 0u;
  __syncthreads();
  const uint4* idv = (const uint4*)(ids + (size_t)b * NPIX);
  for (int t = tid; t < NPIX / 4; t += 1024) {
    uint4 v = idv[t];
    if ((v.x >> 14) == w) atomicAdd(&sh[v.x & 16383u], 1u);
    if ((v.y >> 14) == w) atomicAdd(&sh[v.y & 16383u], 1u);
    if ((v.z >> 14) == w) atomicAdd(&sh[v.z & 16383u], 1u);
    if ((v.w >> 14) == w) atomicAdd(&sh[v.w & 16383u], 1u);
  }
  __syncthreads();
  uint4* dst = (uint4*)(Hh + ((size_t)b * nwin + w) * WINWORDS);
  const uint4* src = (const uint4*)sh;
  for (int t = tid; t < WINWORDS / 4; t += 1024) dst[t] = src[t];
}

// ---------------- stage B: M[b][q][i][g] = sum_{j in q-slice} H[i][j] * K[j][g] ----------------
__global__ __launch_bounds__(256) void stageB(const unsigned int* __restrict__ Hh,
                                              const float* __restrict__ kt,
                                              float* __restrict__ M, int W, int Q) {
  int ntile = W >> 6;
  int bid = blockIdx.x;
  int q = bid % Q;
  int itile = (bid / Q) % ntile;
  int b = bid / (Q * ntile);
  __shared__ float sH[64][65];   // +1 pad: conflict-free row reads
  __shared__ float sK[64][64];   // read as float4, 16 distinct addrs/wave
  int tid = threadIdx.x;
  int gq4 = (tid & 15) * 4;
  int iq4 = (tid >> 4) * 4;
  float acc[4][4];
#pragma unroll
  for (int a = 0; a < 4; a++)
#pragma unroll
    for (int c = 0; c < 4; c++) acc[a][c] = 0.0f;

  int jspan = W / Q;            // 128
  int jbase = q * jspan;
  int nchunk = jspan >> 6;      // 2
  const unsigned int* Hbase = Hh + ((size_t)b * W + (size_t)itile * 64) * W;

  for (int ch = 0; ch < nchunk; ch++) {
    int j0 = jbase + ch * 64;
#pragma unroll
    for (int rep = 0; rep < 16; rep++) {
      int idx = rep * 256 + tid;
      int ii = idx >> 6, jj = idx & 63;
      sH[ii][jj] = (float)Hbase[(size_t)ii * W + (j0 + jj)];
      sK[ii][jj] = kt[(size_t)(j0 + ii) * HB + jj];
    }
    __syncthreads();
#pragma unroll 8
    for (int jp = 0; jp < 64; jp++) {
      float4 kv = *(const float4*)&sK[jp][gq4];
      float h[4];
#pragma unroll
      for (int di = 0; di < 4; di++) h[di] = sH[iq4 + di][jp];
      float kk[4] = {kv.x, kv.y, kv.z, kv.w};
#pragma unroll
      for (int di = 0; di < 4; di++)
#pragma unroll
        for (int dg = 0; dg < 4; dg++)
          acc[di][dg] = fmaf(h[di], kk[dg], acc[di][dg]);
    }
    __syncthreads();
  }

  float* Mb = M + (((size_t)b * Q + q) * W + (size_t)itile * 64) * HB;
#pragma unroll
  for (int di = 0; di < 4; di++) {
    float4 v = make_float4(acc[di][0], acc[di][1], acc[di][2], acc[di][3]);
    *(float4*)&Mb[(size_t)(iq4 + di) * HB + gq4] = v;
  }
}

// ---------------- stage C: partial hist P[b][chunk][r][g] = sum_{i in chunk} K[i][r] * Msum[i][g] ----------------
__global__ __launch_bounds__(1024) void stageC(const float* __restrict__ M,
                                               const float* __restrict__ kt,
                                               float* __restrict__ P, int W, int Q) {
  int ntile = W >> 6;
  int b = blockIdx.x / ntile;
  int cti = blockIdx.x % ntile;
  int i0 = cti * 64;
  __shared__ float sM[64][64];
  __shared__ float sK[64][65];
  int tid = threadIdx.x;
  int r = tid >> 4;
  int g4 = (tid & 15) * 4;
#pragma unroll
  for (int rep = 0; rep < 4; rep++) {
    int idx = rep * 1024 + tid;
    int ii = idx >> 6, cc = idx & 63;
    float v = 0.0f;
    for (int q = 0; q < Q; q++)
      v += M[(((size_t)b * Q + q) * W + (i0 + ii)) * HB + cc];
    sM[ii][cc] = v;
    sK[ii][cc] = kt[(size_t)(i0 + ii) * HB + cc];
  }
  __syncthreads();
  float a0 = 0, a1 = 0, a2 = 0, a3 = 0;
#pragma unroll 8
  for (int ip = 0; ip < 64; ip++) {
    float kv = sK[ip][r];
    float4 m = *(const float4*)&sM[ip][g4];
    a0 = fmaf(kv, m.x, a0);
    a1 = fmaf(kv, m.y, a1);
    a2 = fmaf(kv, m.z, a2);
    a3 = fmaf(kv, m.w, a3);
  }
  float* Pb = P + ((size_t)b * ntile + cti) * 4096;
  *(float4*)&Pb[(size_t)r * 64 + g4] = make_float4(a0, a1, a2, a3);
}

// ---------------- stage D: fixed-order reduce over chunks + normalize ----------------
__global__ __launch_bounds__(256) void stageD(const float* __restrict__ P,
                                              float* __restrict__ out, int W) {
  int ntile = W >> 6;
  int b = blockIdx.x;
  int tid = threadIdx.x;
  const float* Pb = P + (size_t)b * ntile * 4096;
  float un[16];
  float psum = 0.0f;
#pragma unroll
  for (int t = 0; t < 16; t++) {
    int rg = t * 256 + tid;
    float s = 0.0f;
    for (int c = 0; c < ntile; c++) s += Pb[(size_t)c * 4096 + rg];
    un[t] = s;
    psum += s;
  }
  __shared__ float red[256];
  red[tid] = psum;
  __syncthreads();
  for (int s = 128; s > 0; s >>= 1) {
    if (tid < s) red[tid] += red[tid + s];
    __syncthreads();
  }
  float inv = 1.0f / (red[0] + EPS);
#pragma unroll
  for (int t = 0; t < 16; t++) {
    out[(size_t)b * 4096 + t * 256 + tid] = un[t] * inv;
  }
}

extern "C" void kernel_launch(void* const* d_in, const int* in_sizes, int n_in,
                              void* d_out, int out_size, void* d_ws, size_t ws_size,
                              hipStream_t stream) {
  const float* x = (const float*)d_in[0];
  float* out = (float*)d_out;

  // choose fine-grid size W by available workspace (512 preferred)
  int W = 512;
  for (;;) {
    int Qtry = W >> 7;
    if (Qtry < 1) Qtry = 1;
    size_t need = (size_t)W * HB * 4                    // K table
                + (size_t)BATCH * W * W * 4             // H counts
                + (size_t)BATCH * NPIX * 4              // pixel ids
                + (size_t)BATCH * Qtry * W * HB * 4     // M partials
                + (size_t)BATCH * (W >> 6) * 4096 * 4;  // P partial hists
    if (need <= ws_size || W == 128) break;
    W >>= 1;
  }
  int Q = W >> 7;        // j-slices in stage B (parallelism)
  if (Q < 1) Q = 1;
  int ntile = W >> 6;
  int nwin = (W * W) / WINWORDS;
  if (nwin < 1) nwin = 1;

  char* p = (char*)d_ws;
  float* kt = (float*)p;               p += (size_t)W * HB * 4;
  unsigned int* Hh = (unsigned int*)p; p += (size_t)BATCH * W * W * 4;
  unsigned int* ids = (unsigned int*)p; p += (size_t)BATCH * NPIX * 4;
  float* M = (float*)p;                p += (size_t)BATCH * Q * W * HB * 4;
  float* P = (float*)p;

  build_ktable<<<(W * HB + 255) / 256, 256, 0, stream>>>(kt, W);
  make_ids<<<BATCH * (NPIX / 4) / 256, 256, 0, stream>>>(x, ids, W);
  hist_window<<<BATCH * nwin, 1024, 0, stream>>>(ids, Hh, nwin);
  stageB<<<BATCH * ntile * Q, 256, 0, stream>>>(Hh, kt, M, W, Q);
  stageC<<<BATCH * ntile, 1024, 0, stream>>>(M, kt, P, W, Q);
  stageD<<<BATCH, 256, 0, stream>>>(P, out, W);
}